// Round 11
// baseline (823.666 us; speedup 1.0000x reference)
//
#include <hip/hip_runtime.h>
#include <hip/hip_fp16.h>
#include <cstdint>
#include <cstddef>

#define NUM_GRAPHS 64
#define HDIM 128
#define NBLK_S 256   // blocks for histogram/scatter passes

typedef __attribute__((ext_vector_type(8))) _Float16 half8v;
typedef __attribute__((ext_vector_type(4))) float float4v;

// ---------------------------------------------------------------------------
// count in-degree + per-(block,bucket) histogram for the bucket sort.
__global__ __launch_bounds__(256) void count_hist_kernel(const int* __restrict__ dst,
                                                         int* __restrict__ cnt,
                                                         int* __restrict__ hist,
                                                         int E, int chunk, int shift, int NB) {
    __shared__ int lh[256];
    int t = threadIdx.x;
    int b = blockIdx.x;
    lh[t] = 0;
    __syncthreads();
    int beg = b * chunk;
    int end = beg + chunk; if (end > E) end = E;
    for (int i = beg + t; i < end; i += 256) {
        int d = dst[i];
        atomicAdd(&cnt[d], 1);
        atomicAdd(&lh[d >> shift], 1);
    }
    __syncthreads();
    for (int k = t; k < NB; k += 256) hist[k * NBLK_S + b] = lh[k];
}

// --- hierarchical scan pieces ---
__global__ __launch_bounds__(256) void scan_partial_kernel(const int* __restrict__ in,
                                                           int* __restrict__ blockSums, int M) {
    __shared__ int s[256];
    int t = threadIdx.x;
    int base = blockIdx.x * 4096 + t * 16;
    int local = 0;
#pragma unroll
    for (int i = 0; i < 16; ++i) {
        int idx = base + i;
        if (idx < M) local += in[idx];
    }
    s[t] = local;
    __syncthreads();
    for (int off = 128; off > 0; off >>= 1) {
        if (t < off) s[t] += s[t + off];
        __syncthreads();
    }
    if (t == 0) blockSums[blockIdx.x] = s[0];
}

__global__ __launch_bounds__(1024) void scan_blocksums_kernel(int* __restrict__ blockSums,
                                                              int* __restrict__ row_ptr_or_null,
                                                              int nb, int E, int N) {
    __shared__ int s[1024];
    int t = threadIdx.x;
    int v = (t < nb) ? blockSums[t] : 0;
    s[t] = v;
    __syncthreads();
    for (int off = 1; off < 1024; off <<= 1) {
        int u = (t >= off) ? s[t - off] : 0;
        __syncthreads();
        s[t] += u;
        __syncthreads();
    }
    if (t < nb) blockSums[t] = s[t] - v;  // exclusive
    if (t == 0 && row_ptr_or_null) row_ptr_or_null[N] = E;
}

__global__ __launch_bounds__(256) void scan_apply_kernel(const int* __restrict__ cnt,
                                                         const int* __restrict__ blockSums,
                                                         int* __restrict__ row_ptr,
                                                         int* __restrict__ fill,
                                                         float* __restrict__ dis, int N) {
    __shared__ int s[256];
    int t = threadIdx.x;
    int base = blockIdx.x * 4096 + t * 16;
    int c[16];
    int local = 0;
#pragma unroll
    for (int i = 0; i < 16; ++i) {
        int idx = base + i;
        c[i] = (idx < N) ? cnt[idx] : 0;
        local += c[i];
    }
    s[t] = local;
    __syncthreads();
    for (int off = 1; off < 256; off <<= 1) {
        int u = (t >= off) ? s[t - off] : 0;
        __syncthreads();
        s[t] += u;
        __syncthreads();
    }
    int pos = blockSums[blockIdx.x] + s[t] - local;
#pragma unroll
    for (int i = 0; i < 16; ++i) {
        int idx = base + i;
        if (idx < N) {
            row_ptr[idx] = pos;
            fill[idx] = pos;
            dis[idx] = rsqrtf((float)c[i] + 1.0f);
            pos += c[i];
        }
    }
}

__global__ __launch_bounds__(256) void scan_apply_generic(int* __restrict__ io,
                                                          const int* __restrict__ blockSums, int M) {
    __shared__ int s[256];
    int t = threadIdx.x;
    int base = blockIdx.x * 4096 + t * 16;
    int c[16];
    int local = 0;
#pragma unroll
    for (int i = 0; i < 16; ++i) {
        int idx = base + i;
        c[i] = (idx < M) ? io[idx] : 0;
        local += c[i];
    }
    s[t] = local;
    __syncthreads();
    for (int off = 1; off < 256; off <<= 1) {
        int u = (t >= off) ? s[t - off] : 0;
        __syncthreads();
        s[t] += u;
        __syncthreads();
    }
    int pos = blockSums[blockIdx.x] + s[t] - local;
#pragma unroll
    for (int i = 0; i < 16; ++i) {
        int idx = base + i;
        if (idx < M) {
            io[idx] = pos;
            pos += c[i];
        }
    }
}

// scatter edges into bucket-grouped pair array
__global__ __launch_bounds__(256) void scatter_bucket_kernel(const int* __restrict__ src,
                                                             const int* __restrict__ dst,
                                                             const int* __restrict__ hist,
                                                             int2* __restrict__ pairs,
                                                             int E, int chunk, int shift, int NB) {
    __shared__ int base[256];
    int t = threadIdx.x;
    int b = blockIdx.x;
    for (int k = t; k < NB; k += 256) base[k] = hist[k * NBLK_S + b];
    __syncthreads();
    int beg = b * chunk;
    int end = beg + chunk; if (end > E) end = E;
    for (int i = beg + t; i < end; i += 256) {
        int d = dst[i];
        int s = src[i];
        int pos = atomicAdd(&base[d >> shift], 1);
        pairs[pos] = make_int2(s, d);
    }
}

// final CSR fill over bucket-grouped pairs
__global__ __launch_bounds__(256) void fill_pairs_kernel(const int2* __restrict__ pairs,
                                                         int* __restrict__ fill,
                                                         int* __restrict__ sorted_src, int E) {
    int i = blockIdx.x * 256 + threadIdx.x;
    if (i < E) {
        int2 p = pairs[i];
        int pos = atomicAdd(&fill[p.y], 1);
        sorted_src[pos] = p.x;
    }
}

// ---------------------------------------------------------------------------
// Fold BN(eval)+conv bias into scale/bias per (layer, feature)
__global__ __launch_bounds__(256) void fold_kernel(const float* __restrict__ gamma,
                                                   const float* __restrict__ beta,
                                                   const float* __restrict__ mean,
                                                   const float* __restrict__ var,
                                                   const float* __restrict__ convb,
                                                   float* __restrict__ scale,
                                                   float* __restrict__ bias, int LH) {
    int i = blockIdx.x * 256 + threadIdx.x;
    if (i < LH) {
        float gs = gamma[i] * rsqrtf(var[i] + 1e-5f);
        scale[i] = gs;
        bias[i] = (convb[i] - mean[i]) * gs + beta[i];
    }
}

// ---------------------------------------------------------------------------
// Pack W[l] into MFMA B-fragment layout, split f16 hi + f16 lo.
__global__ __launch_bounds__(64) void pack_W_kernel(const float* __restrict__ W,
                                                    __half* __restrict__ hi,
                                                    __half* __restrict__ lo) {
    int b = blockIdx.x;         // l*32 + ntile*4 + kchunk
    int l = b >> 5;
    int ntile = (b >> 2) & 7;
    int kchunk = b & 3;
    int lane = threadIdx.x;
    int n = ntile * 16 + (lane & 15);
    int kbase = kchunk * 32 + (lane >> 4) * 8;
    size_t ob = ((size_t)b * 64 + lane) * 8;
#pragma unroll
    for (int j = 0; j < 8; ++j) {
        float w = W[(size_t)l * 16384 + (size_t)(kbase + j) * 128 + n];
        __half hb = __float2half_rn(w);
        float rem = w - __half2float(hb);
        hi[ob + j] = hb;
        lo[ob + j] = __float2half_rn(rem);
    }
}

// ---------------------------------------------------------------------------
// MFMA GEMM (f16, split-W): out16[n] = f16( dis[n] * (h[n] @ W) )
__global__ __launch_bounds__(256) void gemm_mfma_f16(const __half* __restrict__ h16,
                                                     const float* __restrict__ h32,
                                                     const __half* __restrict__ Whi,
                                                     const __half* __restrict__ Wlo,
                                                     const float* __restrict__ dis,
                                                     __half* __restrict__ out, int N) {
    int wave = threadIdx.x >> 6;
    int lane = threadIdx.x & 63;
    int lrow = lane & 15;
    int lk8 = lane >> 4;
    int mbase = blockIdx.x * 128 + wave * 32;

    float4v acc[2][8];
#pragma unroll
    for (int mt = 0; mt < 2; ++mt)
#pragma unroll
        for (int nt = 0; nt < 8; ++nt) {
            acc[mt][nt][0] = 0.f; acc[mt][nt][1] = 0.f;
            acc[mt][nt][2] = 0.f; acc[mt][nt][3] = 0.f;
        }

    const half8v* BH = (const half8v*)Whi;
    const half8v* BL = (const half8v*)Wlo;
    const half8v* H8 = (const half8v*)h16;

    for (int kc = 0; kc < 4; ++kc) {
        half8v a[2];
#pragma unroll
        for (int mt = 0; mt < 2; ++mt) {
            int node = mbase + mt * 16 + lrow;
            if (node < N) {
                if (h32) {
                    const float4* hp = (const float4*)&h32[(size_t)node * HDIM + kc * 32 + lk8 * 8];
                    float4 f0 = hp[0], f1 = hp[1];
                    a[mt][0] = (_Float16)f0.x; a[mt][1] = (_Float16)f0.y;
                    a[mt][2] = (_Float16)f0.z; a[mt][3] = (_Float16)f0.w;
                    a[mt][4] = (_Float16)f1.x; a[mt][5] = (_Float16)f1.y;
                    a[mt][6] = (_Float16)f1.z; a[mt][7] = (_Float16)f1.w;
                } else {
                    a[mt] = H8[(size_t)node * 16 + kc * 4 + lk8];
                }
            } else {
#pragma unroll
                for (int j = 0; j < 8; ++j) a[mt][j] = (_Float16)0;
            }
        }
#pragma unroll
        for (int nt = 0; nt < 8; ++nt) {
            half8v bh = BH[(size_t)(nt * 4 + kc) * 64 + lane];
            half8v bl = BL[(size_t)(nt * 4 + kc) * 64 + lane];
#pragma unroll
            for (int mt = 0; mt < 2; ++mt) {
                acc[mt][nt] = __builtin_amdgcn_mfma_f32_16x16x32_f16(a[mt], bh, acc[mt][nt], 0, 0, 0);
                acc[mt][nt] = __builtin_amdgcn_mfma_f32_16x16x32_f16(a[mt], bl, acc[mt][nt], 0, 0, 0);
            }
        }
    }

#pragma unroll
    for (int mt = 0; mt < 2; ++mt) {
#pragma unroll
        for (int r = 0; r < 4; ++r) {
            int node = mbase + mt * 16 + lk8 * 4 + r;
            if (node < N) {
                float dn = dis[node];
#pragma unroll
                for (int nt = 0; nt < 8; ++nt)
                    out[(size_t)node * HDIM + nt * 16 + lrow] = __float2half_rn(acc[mt][nt][r] * dn);
            }
        }
    }
}

// ---------------------------------------------------------------------------
// Aggregate v3: one wave per node; two half-waves gather two edges per load.
// 16-edge main loop: 8 row-loads issued back-to-back -> 8 in flight per wave.
__device__ inline void acc_add8(float4& a, uint2 v) {
    float2 f0 = __half22float2(*(__half2*)&v.x);
    float2 f1 = __half22float2(*(__half2*)&v.y);
    a.x += f0.x; a.y += f0.y; a.z += f1.x; a.w += f1.y;
}

__global__ __launch_bounds__(256) void agg_kernel(const __half* __restrict__ hwp,
                                                  const int* __restrict__ row_ptr,
                                                  const int* __restrict__ ss,
                                                  const float* __restrict__ dis,
                                                  const float* __restrict__ scale,
                                                  const float* __restrict__ bias,
                                                  __half* __restrict__ hout, int N) {
    int wave = threadIdx.x >> 6;
    int lane = threadIdx.x & 63;
    int n = blockIdx.x * 4 + wave;
    if (n >= N) return;
    int hid = lane >> 5;     // which half of the wave
    int l32 = lane & 31;
    const uint2* rows = (const uint2*)hwp;  // row = 32 x uint2 (8B per lane)

    float4 acc0 = make_float4(0.f, 0.f, 0.f, 0.f);
    float4 acc1 = make_float4(0.f, 0.f, 0.f, 0.f);

    // self term: half 0 only
    if (hid == 0) {
        uint2 sv = rows[(size_t)n * 32 + l32];
        acc_add8(acc0, sv);
    }

    int e0 = row_ptr[n];
    int e1 = row_ptr[n + 1];
    int e = e0;

    // 16 edges / iter: 8 independent row-gathers in flight
    for (; e + 15 < e1; e += 16) {
        int s[16];
#pragma unroll
        for (int i = 0; i < 16; ++i) s[i] = ss[e + i];
        uint2 v[8];
#pragma unroll
        for (int i = 0; i < 8; ++i) {
            int q = hid ? s[2 * i + 1] : s[2 * i];
            v[i] = rows[(size_t)q * 32 + l32];
        }
#pragma unroll
        for (int i = 0; i < 8; ++i) acc_add8((i & 1) ? acc1 : acc0, v[i]);
    }
    // 8 edges / iter: 4 in flight
    for (; e + 7 < e1; e += 8) {
        int s[8];
#pragma unroll
        for (int i = 0; i < 8; ++i) s[i] = ss[e + i];
        uint2 v[4];
#pragma unroll
        for (int i = 0; i < 4; ++i) {
            int q = hid ? s[2 * i + 1] : s[2 * i];
            v[i] = rows[(size_t)q * 32 + l32];
        }
#pragma unroll
        for (int i = 0; i < 4; ++i) acc_add8((i & 1) ? acc1 : acc0, v[i]);
    }
    for (; e + 1 < e1; e += 2) {
        int sA = ss[e], sB = ss[e + 1];
        int q0 = hid ? sB : sA;
        uint2 v0 = rows[(size_t)q0 * 32 + l32];
        acc_add8(acc0, v0);
    }
    if (e < e1) {
        if (hid == 0) {
            int sA = ss[e];
            uint2 v0 = rows[(size_t)sA * 32 + l32];
            acc_add8(acc1, v0);
        }
    }
    acc0.x += acc1.x; acc0.y += acc1.y; acc0.z += acc1.z; acc0.w += acc1.w;

    acc0.x += __shfl_xor(acc0.x, 32);
    acc0.y += __shfl_xor(acc0.y, 32);
    acc0.z += __shfl_xor(acc0.z, 32);
    acc0.w += __shfl_xor(acc0.w, 32);

    if (hid == 0) {
        float dn = dis[n];
        int f0 = l32 * 4;
        float4 sc = *(const float4*)&scale[f0];
        float4 bs = *(const float4*)&bias[f0];
        float y0 = fmaxf(dn * acc0.x * sc.x + bs.x, 0.f);
        float y1 = fmaxf(dn * acc0.y * sc.y + bs.y, 0.f);
        float y2 = fmaxf(dn * acc0.z * sc.z + bs.z, 0.f);
        float y3 = fmaxf(dn * acc0.w * sc.w + bs.w, 0.f);
        __half2 o0 = __floats2half2_rn(y0, y1);
        __half2 o1 = __floats2half2_rn(y2, y3);
        uint2 ov;
        ov.x = *(unsigned*)&o0;
        ov.y = *(unsigned*)&o1;
        ((uint2*)hout)[(size_t)n * 32 + l32] = ov;
    }
}

// ---------------------------------------------------------------------------
// Global add pool v2: 64 nodes/block, 256 thr = 4 groups x 64 lanes.
__global__ __launch_bounds__(256) void pool_kernel(const __half* __restrict__ h,
                                                   const int* __restrict__ batch,
                                                   float* __restrict__ pooled, int N) {
    int t = threadIdx.x;
    int grp = t >> 6;
    int lane = t & 63;
    int n0 = blockIdx.x * 64 + grp * 16;
    if (n0 >= N) return;
    int nend = n0 + 16; if (nend > N) nend = N;
    const __half2* h2 = (const __half2*)h;

    float2 acc = make_float2(0.f, 0.f);
    int cur = batch[n0];
    for (int n = n0; n < nend; ++n) {
        int gn = batch[n];
        if (gn != cur) {
            atomicAdd(&pooled[cur * HDIM + lane * 2], acc.x);
            atomicAdd(&pooled[cur * HDIM + lane * 2 + 1], acc.y);
            acc = make_float2(0.f, 0.f);
            cur = gn;
        }
        float2 v = __half22float2(h2[(size_t)n * 64 + lane]);
        acc.x += v.x;
        acc.y += v.y;
    }
    atomicAdd(&pooled[cur * HDIM + lane * 2], acc.x);
    atomicAdd(&pooled[cur * HDIM + lane * 2 + 1], acc.y);
}

// ---------------------------------------------------------------------------
// Heads: one block per graph.
__global__ __launch_bounds__(128) void head_kernel(const float* __restrict__ pooled,
                                                   const float* __restrict__ cW1, const float* __restrict__ cb1,
                                                   const float* __restrict__ cW2, const float* __restrict__ cb2,
                                                   const float* __restrict__ nW1, const float* __restrict__ nb1,
                                                   const float* __restrict__ nW2, const float* __restrict__ nb2,
                                                   float* __restrict__ out) {
    __shared__ float p[128];
    __shared__ float hid[128];
    int g = blockIdx.x, t = threadIdx.x;
    p[t] = pooled[g * HDIM + t];
    __syncthreads();

    float a = cb1[t];
    for (int k = 0; k < 128; ++k) a += p[k] * cW1[k * 128 + t];
    hid[t] = fmaxf(a, 0.f);
    __syncthreads();
    if (t < 16) {
        float acc = cb2[t];
        for (int j = 0; j < 128; ++j) acc += hid[j] * cW2[j * 16 + t];
        out[g * 16 + t] = acc;
    }
    __syncthreads();

    float b = nb1[t];
    for (int k = 0; k < 128; ++k) b += p[k] * nW1[k * 128 + t];
    hid[t] = fmaxf(b, 0.f);
    __syncthreads();
    if (t == 0) {
        float acc = nb2[0];
        for (int j = 0; j < 128; ++j) acc += hid[j] * nW2[j];
        out[NUM_GRAPHS * 16 + g] = 1.f / (1.f + expf(-acc));
    }
}

// ---------------------------------------------------------------------------
extern "C" void kernel_launch(void* const* d_in, const int* in_sizes, int n_in,
                              void* d_out, int out_size, void* d_ws, size_t ws_size,
                              hipStream_t stream) {
    const float* x       = (const float*)d_in[0];
    const int*   ei      = (const int*)d_in[1];
    const int*   batch   = (const int*)d_in[2];
    const float* conv_W  = (const float*)d_in[3];
    const float* conv_b  = (const float*)d_in[4];
    const float* bn_g    = (const float*)d_in[5];
    const float* bn_b    = (const float*)d_in[6];
    const float* bn_m    = (const float*)d_in[7];
    const float* bn_v    = (const float*)d_in[8];
    const float* cW1     = (const float*)d_in[9];
    const float* cb1     = (const float*)d_in[10];
    const float* cW2     = (const float*)d_in[11];
    const float* cb2     = (const float*)d_in[12];
    const float* nW1     = (const float*)d_in[13];
    const float* nb1     = (const float*)d_in[14];
    const float* nW2     = (const float*)d_in[15];
    const float* nb2     = (const float*)d_in[16];

    const int N = in_sizes[2];
    const int E = in_sizes[1] / 2;
    const int L = in_sizes[3] / (128 * 128);
    const int H = HDIM;

    const int* src = ei;
    const int* dst = ei + E;

    int shift = 9;
    while ((((N - 1) >> shift) + 1) > 256) ++shift;
    const int NB = ((N - 1) >> shift) + 1;
    const int M = NB * NBLK_S;
    const int chunk = (E + NBLK_S - 1) / NBLK_S;

    char* w = (char*)d_ws;
    size_t o = 0;
    auto alloc = [&](size_t bytes) -> void* {
        void* p = w + o;
        o = (o + bytes + 255) & ~(size_t)255;
        return p;
    };
    int nscanN = (N + 4095) / 4096;
    int nscanM = (M + 4095) / 4096;
    int nscanMax = nscanN > nscanM ? nscanN : nscanM;

    int*    cnt        = (int*)alloc((size_t)N * 4);
    int*    fill       = (int*)alloc((size_t)N * 4);
    int*    row_ptr    = (int*)alloc((size_t)(N + 1) * 4);
    float*  dis        = (float*)alloc((size_t)N * 4);
    float*  scale      = (float*)alloc((size_t)L * H * 4);
    float*  bias       = (float*)alloc((size_t)L * H * 4);
    int*    blockSums  = (int*)alloc((size_t)nscanMax * 4);
    int*    hist       = (int*)alloc((size_t)M * 4);
    int2*   pairs      = (int2*)alloc((size_t)E * 8);
    int*    sorted_src = (int*)alloc((size_t)E * 4);
    __half* Whi        = (__half*)alloc((size_t)L * H * H * 2);
    __half* Wlo        = (__half*)alloc((size_t)L * H * H * 2);
    __half* bufA       = (__half*)alloc((size_t)N * H * 2);  // hw' table
    __half* bufB       = (__half*)alloc((size_t)N * H * 2);  // h
    float*  pooled     = (float*)alloc((size_t)NUM_GRAPHS * H * 4);

    hipMemsetAsync(cnt, 0, (size_t)N * 4, stream);
    hipMemsetAsync(pooled, 0, (size_t)NUM_GRAPHS * H * 4, stream);

    count_hist_kernel<<<NBLK_S, 256, 0, stream>>>(dst, cnt, hist, E, chunk, shift, NB);
    scan_partial_kernel<<<nscanN, 256, 0, stream>>>(cnt, blockSums, N);
    scan_blocksums_kernel<<<1, 1024, 0, stream>>>(blockSums, row_ptr, nscanN, E, N);
    scan_apply_kernel<<<nscanN, 256, 0, stream>>>(cnt, blockSums, row_ptr, fill, dis, N);
    scan_partial_kernel<<<nscanM, 256, 0, stream>>>(hist, blockSums, M);
    scan_blocksums_kernel<<<1, 1024, 0, stream>>>(blockSums, nullptr, nscanM, 0, 0);
    scan_apply_generic<<<nscanM, 256, 0, stream>>>(hist, blockSums, M);
    scatter_bucket_kernel<<<NBLK_S, 256, 0, stream>>>(src, dst, hist, pairs, E, chunk, shift, NB);
    fill_pairs_kernel<<<(E + 255) / 256, 256, 0, stream>>>(pairs, fill, sorted_src, E);

    fold_kernel<<<(L * H + 255) / 256, 256, 0, stream>>>(bn_g, bn_b, bn_m, bn_v, conv_b,
                                                         scale, bias, L * H);
    pack_W_kernel<<<L * 32, 64, 0, stream>>>(conv_W, Whi, Wlo);

    const __half* hin = nullptr;  // layer 0 reads x (fp32) directly
    for (int l = 0; l < L; ++l) {
        gemm_mfma_f16<<<(N + 127) / 128, 256, 0, stream>>>(hin, l == 0 ? x : nullptr,
                                                           Whi + (size_t)l * H * H,
                                                           Wlo + (size_t)l * H * H,
                                                           dis, bufA, N);
        agg_kernel<<<(N + 3) / 4, 256, 0, stream>>>(bufA, row_ptr, sorted_src, dis,
                                                    scale + l * H, bias + l * H, bufB, N);
        hin = bufB;
    }

    pool_kernel<<<(N + 63) / 64, 256, 0, stream>>>(bufB, batch, pooled, N);
    head_kernel<<<NUM_GRAPHS, 128, 0, stream>>>(pooled, cW1, cb1, cW2, cb2,
                                                nW1, nb1, nW2, nb2, (float*)d_out);
}

// Round 12
// 695.806 us; speedup vs baseline: 1.1838x; 1.1838x over previous
//
#include <hip/hip_runtime.h>
#include <hip/hip_fp16.h>
#include <cstdint>
#include <cstddef>

#define NUM_GRAPHS 64
#define HDIM 128
#define NBLK_S 256   // blocks for histogram/scatter passes

typedef __attribute__((ext_vector_type(8))) _Float16 half8v;
typedef __attribute__((ext_vector_type(4))) float float4v;

// ---------------------------------------------------------------------------
// count in-degree + per-(block,bucket) histogram for the bucket sort.
__global__ __launch_bounds__(256) void count_hist_kernel(const int* __restrict__ dst,
                                                         int* __restrict__ cnt,
                                                         int* __restrict__ hist,
                                                         int E, int chunk, int shift, int NB) {
    __shared__ int lh[256];
    int t = threadIdx.x;
    int b = blockIdx.x;
    lh[t] = 0;
    __syncthreads();
    int beg = b * chunk;
    int end = beg + chunk; if (end > E) end = E;
    for (int i = beg + t; i < end; i += 256) {
        int d = dst[i];
        atomicAdd(&cnt[d], 1);
        atomicAdd(&lh[d >> shift], 1);
    }
    __syncthreads();
    for (int k = t; k < NB; k += 256) hist[k * NBLK_S + b] = lh[k];
}

// --- hierarchical scan pieces ---
__global__ __launch_bounds__(256) void scan_partial_kernel(const int* __restrict__ in,
                                                           int* __restrict__ blockSums, int M) {
    __shared__ int s[256];
    int t = threadIdx.x;
    int base = blockIdx.x * 4096 + t * 16;
    int local = 0;
#pragma unroll
    for (int i = 0; i < 16; ++i) {
        int idx = base + i;
        if (idx < M) local += in[idx];
    }
    s[t] = local;
    __syncthreads();
    for (int off = 128; off > 0; off >>= 1) {
        if (t < off) s[t] += s[t + off];
        __syncthreads();
    }
    if (t == 0) blockSums[blockIdx.x] = s[0];
}

__global__ __launch_bounds__(1024) void scan_blocksums_kernel(int* __restrict__ blockSums,
                                                              int* __restrict__ row_ptr_or_null,
                                                              int nb, int E, int N) {
    __shared__ int s[1024];
    int t = threadIdx.x;
    int v = (t < nb) ? blockSums[t] : 0;
    s[t] = v;
    __syncthreads();
    for (int off = 1; off < 1024; off <<= 1) {
        int u = (t >= off) ? s[t - off] : 0;
        __syncthreads();
        s[t] += u;
        __syncthreads();
    }
    if (t < nb) blockSums[t] = s[t] - v;  // exclusive
    if (t == 0 && row_ptr_or_null) row_ptr_or_null[N] = E;
}

__global__ __launch_bounds__(256) void scan_apply_kernel(const int* __restrict__ cnt,
                                                         const int* __restrict__ blockSums,
                                                         int* __restrict__ row_ptr,
                                                         int* __restrict__ fill,
                                                         float* __restrict__ dis, int N) {
    __shared__ int s[256];
    int t = threadIdx.x;
    int base = blockIdx.x * 4096 + t * 16;
    int c[16];
    int local = 0;
#pragma unroll
    for (int i = 0; i < 16; ++i) {
        int idx = base + i;
        c[i] = (idx < N) ? cnt[idx] : 0;
        local += c[i];
    }
    s[t] = local;
    __syncthreads();
    for (int off = 1; off < 256; off <<= 1) {
        int u = (t >= off) ? s[t - off] : 0;
        __syncthreads();
        s[t] += u;
        __syncthreads();
    }
    int pos = blockSums[blockIdx.x] + s[t] - local;
#pragma unroll
    for (int i = 0; i < 16; ++i) {
        int idx = base + i;
        if (idx < N) {
            row_ptr[idx] = pos;
            fill[idx] = pos;
            dis[idx] = rsqrtf((float)c[i] + 1.0f);
            pos += c[i];
        }
    }
}

__global__ __launch_bounds__(256) void scan_apply_generic(int* __restrict__ io,
                                                          const int* __restrict__ blockSums, int M) {
    __shared__ int s[256];
    int t = threadIdx.x;
    int base = blockIdx.x * 4096 + t * 16;
    int c[16];
    int local = 0;
#pragma unroll
    for (int i = 0; i < 16; ++i) {
        int idx = base + i;
        c[i] = (idx < M) ? io[idx] : 0;
        local += c[i];
    }
    s[t] = local;
    __syncthreads();
    for (int off = 1; off < 256; off <<= 1) {
        int u = (t >= off) ? s[t - off] : 0;
        __syncthreads();
        s[t] += u;
        __syncthreads();
    }
    int pos = blockSums[blockIdx.x] + s[t] - local;
#pragma unroll
    for (int i = 0; i < 16; ++i) {
        int idx = base + i;
        if (idx < M) {
            io[idx] = pos;
            pos += c[i];
        }
    }
}

// scatter edges into bucket-grouped pair array
__global__ __launch_bounds__(256) void scatter_bucket_kernel(const int* __restrict__ src,
                                                             const int* __restrict__ dst,
                                                             const int* __restrict__ hist,
                                                             int2* __restrict__ pairs,
                                                             int E, int chunk, int shift, int NB) {
    __shared__ int base[256];
    int t = threadIdx.x;
    int b = blockIdx.x;
    for (int k = t; k < NB; k += 256) base[k] = hist[k * NBLK_S + b];
    __syncthreads();
    int beg = b * chunk;
    int end = beg + chunk; if (end > E) end = E;
    for (int i = beg + t; i < end; i += 256) {
        int d = dst[i];
        int s = src[i];
        int pos = atomicAdd(&base[d >> shift], 1);
        pairs[pos] = make_int2(s, d);
    }
}

// final CSR fill over bucket-grouped pairs
__global__ __launch_bounds__(256) void fill_pairs_kernel(const int2* __restrict__ pairs,
                                                         int* __restrict__ fill,
                                                         int* __restrict__ sorted_src, int E) {
    int i = blockIdx.x * 256 + threadIdx.x;
    if (i < E) {
        int2 p = pairs[i];
        int pos = atomicAdd(&fill[p.y], 1);
        sorted_src[pos] = p.x;
    }
}

// ---------------------------------------------------------------------------
// Fold BN(eval)+conv bias into scale/bias per (layer, feature)
__global__ __launch_bounds__(256) void fold_kernel(const float* __restrict__ gamma,
                                                   const float* __restrict__ beta,
                                                   const float* __restrict__ mean,
                                                   const float* __restrict__ var,
                                                   const float* __restrict__ convb,
                                                   float* __restrict__ scale,
                                                   float* __restrict__ bias, int LH) {
    int i = blockIdx.x * 256 + threadIdx.x;
    if (i < LH) {
        float gs = gamma[i] * rsqrtf(var[i] + 1e-5f);
        scale[i] = gs;
        bias[i] = (convb[i] - mean[i]) * gs + beta[i];
    }
}

// ---------------------------------------------------------------------------
// Pack W[l] into MFMA B-fragment layout, split f16 hi + f16 lo.
__global__ __launch_bounds__(64) void pack_W_kernel(const float* __restrict__ W,
                                                    __half* __restrict__ hi,
                                                    __half* __restrict__ lo) {
    int b = blockIdx.x;         // l*32 + ntile*4 + kchunk
    int l = b >> 5;
    int ntile = (b >> 2) & 7;
    int kchunk = b & 3;
    int lane = threadIdx.x;
    int n = ntile * 16 + (lane & 15);
    int kbase = kchunk * 32 + (lane >> 4) * 8;
    size_t ob = ((size_t)b * 64 + lane) * 8;
#pragma unroll
    for (int j = 0; j < 8; ++j) {
        float w = W[(size_t)l * 16384 + (size_t)(kbase + j) * 128 + n];
        __half hb = __float2half_rn(w);
        float rem = w - __half2float(hb);
        hi[ob + j] = hb;
        lo[ob + j] = __float2half_rn(rem);
    }
}

// ---------------------------------------------------------------------------
// MFMA GEMM (f16, split-W): out16[n] = f16( dis[n] * (h[n] @ W) )
__global__ __launch_bounds__(256) void gemm_mfma_f16(const __half* __restrict__ h16,
                                                     const float* __restrict__ h32,
                                                     const __half* __restrict__ Whi,
                                                     const __half* __restrict__ Wlo,
                                                     const float* __restrict__ dis,
                                                     __half* __restrict__ out, int N) {
    int wave = threadIdx.x >> 6;
    int lane = threadIdx.x & 63;
    int lrow = lane & 15;
    int lk8 = lane >> 4;
    int mbase = blockIdx.x * 128 + wave * 32;

    float4v acc[2][8];
#pragma unroll
    for (int mt = 0; mt < 2; ++mt)
#pragma unroll
        for (int nt = 0; nt < 8; ++nt) {
            acc[mt][nt][0] = 0.f; acc[mt][nt][1] = 0.f;
            acc[mt][nt][2] = 0.f; acc[mt][nt][3] = 0.f;
        }

    const half8v* BH = (const half8v*)Whi;
    const half8v* BL = (const half8v*)Wlo;
    const half8v* H8 = (const half8v*)h16;

    for (int kc = 0; kc < 4; ++kc) {
        half8v a[2];
#pragma unroll
        for (int mt = 0; mt < 2; ++mt) {
            int node = mbase + mt * 16 + lrow;
            if (node < N) {
                if (h32) {
                    const float4* hp = (const float4*)&h32[(size_t)node * HDIM + kc * 32 + lk8 * 8];
                    float4 f0 = hp[0], f1 = hp[1];
                    a[mt][0] = (_Float16)f0.x; a[mt][1] = (_Float16)f0.y;
                    a[mt][2] = (_Float16)f0.z; a[mt][3] = (_Float16)f0.w;
                    a[mt][4] = (_Float16)f1.x; a[mt][5] = (_Float16)f1.y;
                    a[mt][6] = (_Float16)f1.z; a[mt][7] = (_Float16)f1.w;
                } else {
                    a[mt] = H8[(size_t)node * 16 + kc * 4 + lk8];
                }
            } else {
#pragma unroll
                for (int j = 0; j < 8; ++j) a[mt][j] = (_Float16)0;
            }
        }
#pragma unroll
        for (int nt = 0; nt < 8; ++nt) {
            half8v bh = BH[(size_t)(nt * 4 + kc) * 64 + lane];
            half8v bl = BL[(size_t)(nt * 4 + kc) * 64 + lane];
#pragma unroll
            for (int mt = 0; mt < 2; ++mt) {
                acc[mt][nt] = __builtin_amdgcn_mfma_f32_16x16x32_f16(a[mt], bh, acc[mt][nt], 0, 0, 0);
                acc[mt][nt] = __builtin_amdgcn_mfma_f32_16x16x32_f16(a[mt], bl, acc[mt][nt], 0, 0, 0);
            }
        }
    }

#pragma unroll
    for (int mt = 0; mt < 2; ++mt) {
#pragma unroll
        for (int r = 0; r < 4; ++r) {
            int node = mbase + mt * 16 + lk8 * 4 + r;
            if (node < N) {
                float dn = dis[node];
#pragma unroll
                for (int nt = 0; nt < 8; ++nt)
                    out[(size_t)node * HDIM + nt * 16 + lrow] = __float2half_rn(acc[mt][nt][r] * dn);
            }
        }
    }
}

// ---------------------------------------------------------------------------
// Aggregate v4: one wave per node; two half-waves gather two edges per load.
// 16-edge main loop with fully NAMED scalars (no arrays -> no PromoteAlloca
// LDS promotion, which cost R11 +17.9M bank conflicts and 123MB scratch).
__device__ inline void acc_add8(float4& a, uint2 v) {
    float2 f0 = __half22float2(*(__half2*)&v.x);
    float2 f1 = __half22float2(*(__half2*)&v.y);
    a.x += f0.x; a.y += f0.y; a.z += f1.x; a.w += f1.y;
}

__global__ __launch_bounds__(256) void agg_kernel(const __half* __restrict__ hwp,
                                                  const int* __restrict__ row_ptr,
                                                  const int* __restrict__ ss,
                                                  const float* __restrict__ dis,
                                                  const float* __restrict__ scale,
                                                  const float* __restrict__ bias,
                                                  __half* __restrict__ hout, int N) {
    int wave = threadIdx.x >> 6;
    int lane = threadIdx.x & 63;
    int n = blockIdx.x * 4 + wave;
    if (n >= N) return;
    int hid = lane >> 5;     // which half of the wave
    int l32 = lane & 31;
    const uint2* rows = (const uint2*)hwp;  // row = 32 x uint2 (8B per lane)

    float4 acc0 = make_float4(0.f, 0.f, 0.f, 0.f);
    float4 acc1 = make_float4(0.f, 0.f, 0.f, 0.f);

    // self term: half 0 only
    if (hid == 0) {
        uint2 sv = rows[(size_t)n * 32 + l32];
        acc_add8(acc0, sv);
    }

    int e0 = row_ptr[n];
    int e1 = row_ptr[n + 1];
    int e = e0;

    // 16 edges / iter: 8 independent row-gathers in flight (all named scalars)
    for (; e + 15 < e1; e += 16) {
        int sA = ss[e + 0],  sB = ss[e + 1],  sC = ss[e + 2],  sD = ss[e + 3];
        int sE = ss[e + 4],  sF = ss[e + 5],  sG = ss[e + 6],  sH = ss[e + 7];
        int sI = ss[e + 8],  sJ = ss[e + 9],  sK = ss[e + 10], sL = ss[e + 11];
        int sM = ss[e + 12], sN = ss[e + 13], sO = ss[e + 14], sP = ss[e + 15];
        int q0 = hid ? sB : sA;
        int q1 = hid ? sD : sC;
        int q2 = hid ? sF : sE;
        int q3 = hid ? sH : sG;
        int q4 = hid ? sJ : sI;
        int q5 = hid ? sL : sK;
        int q6 = hid ? sN : sM;
        int q7 = hid ? sP : sO;
        uint2 v0 = rows[(size_t)q0 * 32 + l32];
        uint2 v1 = rows[(size_t)q1 * 32 + l32];
        uint2 v2 = rows[(size_t)q2 * 32 + l32];
        uint2 v3 = rows[(size_t)q3 * 32 + l32];
        uint2 v4 = rows[(size_t)q4 * 32 + l32];
        uint2 v5 = rows[(size_t)q5 * 32 + l32];
        uint2 v6 = rows[(size_t)q6 * 32 + l32];
        uint2 v7 = rows[(size_t)q7 * 32 + l32];
        acc_add8(acc0, v0);
        acc_add8(acc1, v1);
        acc_add8(acc0, v2);
        acc_add8(acc1, v3);
        acc_add8(acc0, v4);
        acc_add8(acc1, v5);
        acc_add8(acc0, v6);
        acc_add8(acc1, v7);
    }
    // 8 edges / iter: 4 in flight (named scalars)
    for (; e + 7 < e1; e += 8) {
        int sA = ss[e + 0], sB = ss[e + 1], sC = ss[e + 2], sD = ss[e + 3];
        int sE = ss[e + 4], sF = ss[e + 5], sG = ss[e + 6], sH = ss[e + 7];
        int q0 = hid ? sB : sA;
        int q1 = hid ? sD : sC;
        int q2 = hid ? sF : sE;
        int q3 = hid ? sH : sG;
        uint2 v0 = rows[(size_t)q0 * 32 + l32];
        uint2 v1 = rows[(size_t)q1 * 32 + l32];
        uint2 v2 = rows[(size_t)q2 * 32 + l32];
        uint2 v3 = rows[(size_t)q3 * 32 + l32];
        acc_add8(acc0, v0);
        acc_add8(acc1, v1);
        acc_add8(acc0, v2);
        acc_add8(acc1, v3);
    }
    for (; e + 1 < e1; e += 2) {
        int sA = ss[e], sB = ss[e + 1];
        int q0 = hid ? sB : sA;
        uint2 v0 = rows[(size_t)q0 * 32 + l32];
        acc_add8(acc0, v0);
    }
    if (e < e1) {
        if (hid == 0) {
            int sA = ss[e];
            uint2 v0 = rows[(size_t)sA * 32 + l32];
            acc_add8(acc1, v0);
        }
    }
    acc0.x += acc1.x; acc0.y += acc1.y; acc0.z += acc1.z; acc0.w += acc1.w;

    acc0.x += __shfl_xor(acc0.x, 32);
    acc0.y += __shfl_xor(acc0.y, 32);
    acc0.z += __shfl_xor(acc0.z, 32);
    acc0.w += __shfl_xor(acc0.w, 32);

    if (hid == 0) {
        float dn = dis[n];
        int f0 = l32 * 4;
        float4 sc = *(const float4*)&scale[f0];
        float4 bs = *(const float4*)&bias[f0];
        float y0 = fmaxf(dn * acc0.x * sc.x + bs.x, 0.f);
        float y1 = fmaxf(dn * acc0.y * sc.y + bs.y, 0.f);
        float y2 = fmaxf(dn * acc0.z * sc.z + bs.z, 0.f);
        float y3 = fmaxf(dn * acc0.w * sc.w + bs.w, 0.f);
        __half2 o0 = __floats2half2_rn(y0, y1);
        __half2 o1 = __floats2half2_rn(y2, y3);
        uint2 ov;
        ov.x = *(unsigned*)&o0;
        ov.y = *(unsigned*)&o1;
        ((uint2*)hout)[(size_t)n * 32 + l32] = ov;
    }
}

// ---------------------------------------------------------------------------
// Global add pool v2: 64 nodes/block, 256 thr = 4 groups x 64 lanes.
__global__ __launch_bounds__(256) void pool_kernel(const __half* __restrict__ h,
                                                   const int* __restrict__ batch,
                                                   float* __restrict__ pooled, int N) {
    int t = threadIdx.x;
    int grp = t >> 6;
    int lane = t & 63;
    int n0 = blockIdx.x * 64 + grp * 16;
    if (n0 >= N) return;
    int nend = n0 + 16; if (nend > N) nend = N;
    const __half2* h2 = (const __half2*)h;

    float2 acc = make_float2(0.f, 0.f);
    int cur = batch[n0];
    for (int n = n0; n < nend; ++n) {
        int gn = batch[n];
        if (gn != cur) {
            atomicAdd(&pooled[cur * HDIM + lane * 2], acc.x);
            atomicAdd(&pooled[cur * HDIM + lane * 2 + 1], acc.y);
            acc = make_float2(0.f, 0.f);
            cur = gn;
        }
        float2 v = __half22float2(h2[(size_t)n * 64 + lane]);
        acc.x += v.x;
        acc.y += v.y;
    }
    atomicAdd(&pooled[cur * HDIM + lane * 2], acc.x);
    atomicAdd(&pooled[cur * HDIM + lane * 2 + 1], acc.y);
}

// ---------------------------------------------------------------------------
// Heads: one block per graph.
__global__ __launch_bounds__(128) void head_kernel(const float* __restrict__ pooled,
                                                   const float* __restrict__ cW1, const float* __restrict__ cb1,
                                                   const float* __restrict__ cW2, const float* __restrict__ cb2,
                                                   const float* __restrict__ nW1, const float* __restrict__ nb1,
                                                   const float* __restrict__ nW2, const float* __restrict__ nb2,
                                                   float* __restrict__ out) {
    __shared__ float p[128];
    __shared__ float hid[128];
    int g = blockIdx.x, t = threadIdx.x;
    p[t] = pooled[g * HDIM + t];
    __syncthreads();

    float a = cb1[t];
    for (int k = 0; k < 128; ++k) a += p[k] * cW1[k * 128 + t];
    hid[t] = fmaxf(a, 0.f);
    __syncthreads();
    if (t < 16) {
        float acc = cb2[t];
        for (int j = 0; j < 128; ++j) acc += hid[j] * cW2[j * 16 + t];
        out[g * 16 + t] = acc;
    }
    __syncthreads();

    float b = nb1[t];
    for (int k = 0; k < 128; ++k) b += p[k] * nW1[k * 128 + t];
    hid[t] = fmaxf(b, 0.f);
    __syncthreads();
    if (t == 0) {
        float acc = nb2[0];
        for (int j = 0; j < 128; ++j) acc += hid[j] * nW2[j];
        out[NUM_GRAPHS * 16 + g] = 1.f / (1.f + expf(-acc));
    }
}

// ---------------------------------------------------------------------------
extern "C" void kernel_launch(void* const* d_in, const int* in_sizes, int n_in,
                              void* d_out, int out_size, void* d_ws, size_t ws_size,
                              hipStream_t stream) {
    const float* x       = (const float*)d_in[0];
    const int*   ei      = (const int*)d_in[1];
    const int*   batch   = (const int*)d_in[2];
    const float* conv_W  = (const float*)d_in[3];
    const float* conv_b  = (const float*)d_in[4];
    const float* bn_g    = (const float*)d_in[5];
    const float* bn_b    = (const float*)d_in[6];
    const float* bn_m    = (const float*)d_in[7];
    const float* bn_v    = (const float*)d_in[8];
    const float* cW1     = (const float*)d_in[9];
    const float* cb1     = (const float*)d_in[10];
    const float* cW2     = (const float*)d_in[11];
    const float* cb2     = (const float*)d_in[12];
    const float* nW1     = (const float*)d_in[13];
    const float* nb1     = (const float*)d_in[14];
    const float* nW2     = (const float*)d_in[15];
    const float* nb2     = (const float*)d_in[16];

    const int N = in_sizes[2];
    const int E = in_sizes[1] / 2;
    const int L = in_sizes[3] / (128 * 128);
    const int H = HDIM;

    const int* src = ei;
    const int* dst = ei + E;

    int shift = 9;
    while ((((N - 1) >> shift) + 1) > 256) ++shift;
    const int NB = ((N - 1) >> shift) + 1;
    const int M = NB * NBLK_S;
    const int chunk = (E + NBLK_S - 1) / NBLK_S;

    char* w = (char*)d_ws;
    size_t o = 0;
    auto alloc = [&](size_t bytes) -> void* {
        void* p = w + o;
        o = (o + bytes + 255) & ~(size_t)255;
        return p;
    };
    int nscanN = (N + 4095) / 4096;
    int nscanM = (M + 4095) / 4096;
    int nscanMax = nscanN > nscanM ? nscanN : nscanM;

    int*    cnt        = (int*)alloc((size_t)N * 4);
    int*    fill       = (int*)alloc((size_t)N * 4);
    int*    row_ptr    = (int*)alloc((size_t)(N + 1) * 4);
    float*  dis        = (float*)alloc((size_t)N * 4);
    float*  scale      = (float*)alloc((size_t)L * H * 4);
    float*  bias       = (float*)alloc((size_t)L * H * 4);
    int*    blockSums  = (int*)alloc((size_t)nscanMax * 4);
    int*    hist       = (int*)alloc((size_t)M * 4);
    int2*   pairs      = (int2*)alloc((size_t)E * 8);
    int*    sorted_src = (int*)alloc((size_t)E * 4);
    __half* Whi        = (__half*)alloc((size_t)L * H * H * 2);
    __half* Wlo        = (__half*)alloc((size_t)L * H * H * 2);
    __half* bufA       = (__half*)alloc((size_t)N * H * 2);  // hw' table
    __half* bufB       = (__half*)alloc((size_t)N * H * 2);  // h
    float*  pooled     = (float*)alloc((size_t)NUM_GRAPHS * H * 4);

    hipMemsetAsync(cnt, 0, (size_t)N * 4, stream);
    hipMemsetAsync(pooled, 0, (size_t)NUM_GRAPHS * H * 4, stream);

    count_hist_kernel<<<NBLK_S, 256, 0, stream>>>(dst, cnt, hist, E, chunk, shift, NB);
    scan_partial_kernel<<<nscanN, 256, 0, stream>>>(cnt, blockSums, N);
    scan_blocksums_kernel<<<1, 1024, 0, stream>>>(blockSums, row_ptr, nscanN, E, N);
    scan_apply_kernel<<<nscanN, 256, 0, stream>>>(cnt, blockSums, row_ptr, fill, dis, N);
    scan_partial_kernel<<<nscanM, 256, 0, stream>>>(hist, blockSums, M);
    scan_blocksums_kernel<<<1, 1024, 0, stream>>>(blockSums, nullptr, nscanM, 0, 0);
    scan_apply_generic<<<nscanM, 256, 0, stream>>>(hist, blockSums, M);
    scatter_bucket_kernel<<<NBLK_S, 256, 0, stream>>>(src, dst, hist, pairs, E, chunk, shift, NB);
    fill_pairs_kernel<<<(E + 255) / 256, 256, 0, stream>>>(pairs, fill, sorted_src, E);

    fold_kernel<<<(L * H + 255) / 256, 256, 0, stream>>>(bn_g, bn_b, bn_m, bn_v, conv_b,
                                                         scale, bias, L * H);
    pack_W_kernel<<<L * 32, 64, 0, stream>>>(conv_W, Whi, Wlo);

    const __half* hin = nullptr;  // layer 0 reads x (fp32) directly
    for (int l = 0; l < L; ++l) {
        gemm_mfma_f16<<<(N + 127) / 128, 256, 0, stream>>>(hin, l == 0 ? x : nullptr,
                                                           Whi + (size_t)l * H * H,
                                                           Wlo + (size_t)l * H * H,
                                                           dis, bufA, N);
        agg_kernel<<<(N + 3) / 4, 256, 0, stream>>>(bufA, row_ptr, sorted_src, dis,
                                                    scale + l * H, bias + l * H, bufB, N);
        hin = bufB;
    }

    pool_kernel<<<(N + 63) / 64, 256, 0, stream>>>(bufB, batch, pooled, N);
    head_kernel<<<NUM_GRAPHS, 128, 0, stream>>>(pooled, cW1, cb1, cW2, cb2,
                                                nW1, nb1, nW2, nb2, (float*)d_out);
}